// Round 2
// baseline (172.782 us; speedup 1.0000x reference)
//
#include <hip/hip_runtime.h>
#include <hip/hip_bf16.h>

static constexpr int B_ = 64, PAST = 128, FUTURE = 64, HEADS = 4, F_ = 51;
static constexpr int N1 = B_ * PAST;    // 8192
static constexpr int N2 = B_ * FUTURE;  // 4096
static constexpr int E1 = N1 * 16;      // 131072
static constexpr int E2 = N2 * 16;      // 65536
static constexpr int MAXDEG = 64;

// node feature t of _pre(): [emb0[c0] (16) | emb1[c1] (8) | emb2[c2] (24) | num (3)]
__device__ __forceinline__
float node_feat(const int* cat, const float* num, const float* e0, const float* e1,
                const float* e2, int n, int t) {
    if (t < 16) return e0[cat[n * 3 + 0] * 16 + t];
    if (t < 24) return e1[cat[n * 3 + 1] * 8 + (t - 16)];
    if (t < 48) return e2[cat[n * 3 + 2] * 24 + (t - 24)];
    return num[n * 3 + (t - 48)];
}

// Build inverted adjacency (dst -> list of src) for both graphs, self-loops included.
__global__ void k_csr(const int* __restrict__ e1, const int* __restrict__ e2,
                      int* __restrict__ count1, int* __restrict__ slot1,
                      int* __restrict__ count2, int* __restrict__ slot2) {
    int tid = blockIdx.x * blockDim.x + threadIdx.x;
    if (tid < E1) {
        int src = e1[tid], dst = e1[E1 + tid];
        int pos = atomicAdd(&count1[dst], 1);
        if (pos < MAXDEG) slot1[dst * MAXDEG + pos] = src;
    } else if (tid < E1 + N1) {
        int n = tid - E1;
        int pos = atomicAdd(&count1[n], 1);
        if (pos < MAXDEG) slot1[n * MAXDEG + pos] = n;
    } else if (tid < E1 + N1 + E2) {
        int i = tid - E1 - N1;
        int src = e2[i], dst = e2[E2 + i];
        int pos = atomicAdd(&count2[dst], 1);
        if (pos < MAXDEG) slot2[dst * MAXDEG + pos] = src;
    } else if (tid < E1 + N1 + E2 + N2) {
        int n = tid - E1 - N1 - E2;
        int pos = atomicAdd(&count2[n], 1);
        if (pos < MAXDEG) slot2[n * MAXDEG + pos] = n;
    }
}

// One block per node. Blocks [0,8192): past nodes -> h1 = x@g1_lin, a_src, a_dst.
// Blocks [8192,12288): future nodes -> store x2 row (51 floats).
__global__ void k_prep(const int* __restrict__ cat1, const float* __restrict__ num1,
                       const int* __restrict__ cat2, const float* __restrict__ num2,
                       const float* __restrict__ emb0, const float* __restrict__ emb1,
                       const float* __restrict__ emb2,
                       const float* __restrict__ g1_lin, const float* __restrict__ g1_asrc,
                       const float* __restrict__ g1_adst,
                       float* __restrict__ h1, float* __restrict__ asrc1,
                       float* __restrict__ adst1, float* __restrict__ x2g) {
    __shared__ float xrow[F_];
    __shared__ float redS[200];
    __shared__ float redD[200];
    int blk = blockIdx.x, t = threadIdx.x;
    if (blk >= N1) {
        int n = blk - N1;
        if (t < F_) x2g[n * F_ + t] = node_feat(cat2, num2, emb0, emb1, emb2, n, t);
        return;
    }
    int n = blk;
    if (t < F_) xrow[t] = node_feat(cat1, num1, emb0, emb1, emb2, n, t);
    __syncthreads();
    if (t < 200) {
        float acc = 0.f;
        for (int j = 0; j < F_; ++j) acc += xrow[j] * g1_lin[j * 200 + t];
        h1[n * 200 + t] = acc;
        // flat index t == h*50 + c matches att_src/att_dst [4,50] layout
        redS[t] = acc * g1_asrc[t];
        redD[t] = acc * g1_adst[t];
    }
    __syncthreads();
    if (t < 4) {
        float s = 0.f;
        for (int c = 0; c < 50; ++c) s += redS[t * 50 + c];
        asrc1[n * 4 + t] = s;
    } else if (t < 8) {
        int h = t - 4;
        float s = 0.f;
        for (int c = 0; c < 50; ++c) s += redD[h * 50 + c];
        adst1[n * 4 + h] = s;
    }
}

// GAT1 aggregation: one wave (64 lanes) per dst node.
__global__ void k_gat1(const int* __restrict__ count1, const int* __restrict__ slot1,
                       const float* __restrict__ h1, const float* __restrict__ asrc1,
                       const float* __restrict__ adst1, const float* __restrict__ g1_b,
                       float* __restrict__ x1) {
    int wave = (blockIdx.x * blockDim.x + threadIdx.x) >> 6;
    int lane = threadIdx.x & 63;
    if (wave >= N1) return;
    int n = wave;
    int deg = min(count1[n], MAXDEG);
    int my_src = (lane < deg) ? slot1[n * MAXDEG + lane] : 0;
    float ad0 = adst1[n * 4 + 0], ad1 = adst1[n * 4 + 1];
    float ad2 = adst1[n * 4 + 2], ad3 = adst1[n * 4 + 3];
    float ex0 = 0.f, ex1 = 0.f, ex2 = 0.f, ex3 = 0.f;
    if (lane < deg) {
        float e0 = asrc1[my_src * 4 + 0] + ad0;
        float e1 = asrc1[my_src * 4 + 1] + ad1;
        float e2 = asrc1[my_src * 4 + 2] + ad2;
        float e3 = asrc1[my_src * 4 + 3] + ad3;
        e0 = e0 >= 0.f ? e0 : 0.2f * e0;  ex0 = expf(e0);
        e1 = e1 >= 0.f ? e1 : 0.2f * e1;  ex1 = expf(e1);
        e2 = e2 >= 0.f ? e2 : 0.2f * e2;  ex2 = expf(e2);
        e3 = e3 >= 0.f ? e3 : 0.2f * e3;  ex3 = expf(e3);
    }
    float s0 = ex0, s1 = ex1, s2 = ex2, s3 = ex3;
    #pragma unroll
    for (int m = 32; m >= 1; m >>= 1) {
        s0 += __shfl_xor(s0, m);
        s1 += __shfl_xor(s1, m);
        s2 += __shfl_xor(s2, m);
        s3 += __shfl_xor(s3, m);
    }
    float inv0 = 1.f / (s0 + 1e-16f), inv1 = 1.f / (s1 + 1e-16f);
    float inv2 = 1.f / (s2 + 1e-16f), inv3 = 1.f / (s3 + 1e-16f);
    float acc0 = 0.f, acc1 = 0.f, acc2 = 0.f, acc3 = 0.f;
    for (int i = 0; i < deg; ++i) {
        int srci = __shfl(my_src, i);
        float w0 = __shfl(ex0, i) * inv0;
        float w1 = __shfl(ex1, i) * inv1;
        float w2 = __shfl(ex2, i) * inv2;
        float w3 = __shfl(ex3, i) * inv3;
        if (lane < 50) {
            const float* hr = &h1[srci * 200];
            acc0 += w0 * hr[lane];
            acc1 += w1 * hr[50 + lane];
            acc2 += w2 * hr[100 + lane];
            acc3 += w3 * hr[150 + lane];
        }
    }
    if (lane < 50)
        x1[n * 50 + lane] = 0.25f * (acc0 + acc1 + acc2 + acc3) + g1_b[lane];
}

// Projections: P1t[b][k][p] = x1 @ W (transposed store), P2[n][k] = x2[:, :50] @ W.
__global__ void k_proj(const float* __restrict__ x1, const float* __restrict__ x2g,
                       const float* __restrict__ W, float* __restrict__ P1t,
                       float* __restrict__ P2) {
    int tid = blockIdx.x * blockDim.x + threadIdx.x;
    int node = tid >> 6, k = tid & 63;
    if (node < N1) {
        const float* xr = &x1[node * 50];
        float acc = 0.f;
        for (int j = 0; j < 50; ++j) acc += xr[j] * W[j * 64 + k];
        int b = node >> 7, p = node & 127;
        P1t[b * 8192 + k * 128 + p] = acc;
    } else if (node < N1 + N2) {
        int n = node - N1;
        const float* xr = &x2g[n * F_];
        float acc = 0.f;
        for (int j = 0; j < 50; ++j) acc += xr[j] * W[j * 64 + k];
        P2[n * 64 + k] = acc;
    }
}

// Attention over (future, past) pairs + tmp matvec + fused h2 = x2b @ g2_lin.
// One block of 128 threads per (b, f); thread p handles past node p.
__global__ void k_attn(const float* __restrict__ P1t, const float* __restrict__ P2,
                       const int* __restrict__ A, const float* __restrict__ num1,
                       const float* __restrict__ x2g, const float* __restrict__ g2_lin,
                       float* __restrict__ h2g) {
    int b = blockIdx.x >> 6, f = blockIdx.x & 63;
    int p = threadIdx.x;
    __shared__ float p2row[64];
    __shared__ float red[128];
    __shared__ float tsh;
    int n2 = b * 64 + f;
    if (p < 64) p2row[p] = P2[n2 * 64 + p];
    __syncthreads();
    const float* P1b = &P1t[b * 8192];
    float d2 = 0.f;
    for (int k = 0; k < 64; ++k) {
        float d = P1b[k * 128 + p] - p2row[k];
        d2 += d * d;
    }
    int maskv = A[p * 192 + PAST + f];
    float val = maskv ? -d2 : -1e30f;
    red[p] = val; __syncthreads();
    for (int s = 64; s > 0; s >>= 1) {
        if (p < s) red[p] = fmaxf(red[p], red[p + s]);
        __syncthreads();
    }
    float m = red[0]; __syncthreads();
    float w = maskv ? expf(val - m) : 0.f;
    red[p] = w; __syncthreads();
    for (int s = 64; s > 0; s >>= 1) {
        if (p < s) red[p] += red[p + s];
        __syncthreads();
    }
    float den = red[0]; __syncthreads();
    float y = num1[(b * 128 + p) * 3 + 2];  // y_past = x[:, 50] = num1[:, 2]
    red[p] = w * y; __syncthreads();
    for (int s = 64; s > 0; s >>= 1) {
        if (p < s) red[p] += red[p + s];
        __syncthreads();
    }
    if (p == 0) tsh = red[0] / den;
    __syncthreads();
    if (p < 4) {
        float acc = tsh * g2_lin[50 * 4 + p];
        const float* xr = &x2g[n2 * F_];
        for (int j = 0; j < 50; ++j) acc += xr[j] * g2_lin[j * 4 + p];
        h2g[n2 * 4 + p] = acc;
    }
}

// GAT2 aggregation (out_ch=1): one wave per dst node, writes fp32 output.
__global__ void k_gat2(const int* __restrict__ count2, const int* __restrict__ slot2,
                       const float* __restrict__ h2g, const float* __restrict__ g2_asrc,
                       const float* __restrict__ g2_adst, const float* __restrict__ g2_b,
                       float* __restrict__ out) {
    int wave = (blockIdx.x * blockDim.x + threadIdx.x) >> 6;
    int lane = threadIdx.x & 63;
    if (wave >= N2) return;
    int n = wave;
    int deg = min(count2[n], MAXDEG);
    int my_src = (lane < deg) ? slot2[n * MAXDEG + lane] : 0;
    float ex[4], nm[4], adterm[4], as[4];
    #pragma unroll
    for (int h = 0; h < 4; ++h) {
        as[h] = g2_asrc[h];
        adterm[h] = h2g[n * 4 + h] * g2_adst[h];
        ex[h] = 0.f; nm[h] = 0.f;
    }
    if (lane < deg) {
        #pragma unroll
        for (int h = 0; h < 4; ++h) {
            float hs = h2g[my_src * 4 + h];
            float e = hs * as[h] + adterm[h];
            e = e >= 0.f ? e : 0.2f * e;
            float xv = expf(e);
            ex[h] = xv;
            nm[h] = xv * hs;
        }
    }
    #pragma unroll
    for (int m = 32; m >= 1; m >>= 1) {
        #pragma unroll
        for (int h = 0; h < 4; ++h) {
            ex[h] += __shfl_xor(ex[h], m);
            nm[h] += __shfl_xor(nm[h], m);
        }
    }
    if (lane == 0) {
        float o = 0.f;
        #pragma unroll
        for (int h = 0; h < 4; ++h) o += nm[h] / (ex[h] + 1e-16f);
        o = 0.25f * o + g2_b[0];
        out[n] = o;
    }
}

extern "C" void kernel_launch(void* const* d_in, const int* in_sizes, int n_in,
                              void* d_out, int out_size, void* d_ws, size_t ws_size,
                              hipStream_t stream) {
    const int*   cat1    = (const int*)  d_in[0];
    const float* num1    = (const float*)d_in[1];
    const int*   cat2    = (const int*)  d_in[2];
    const float* num2    = (const float*)d_in[3];
    const int*   e1      = (const int*)  d_in[4];
    const int*   e2      = (const int*)  d_in[5];
    const int*   A       = (const int*)  d_in[6];
    const float* emb0    = (const float*)d_in[7];
    const float* emb1    = (const float*)d_in[8];
    const float* emb2    = (const float*)d_in[9];
    const float* g1_lin  = (const float*)d_in[10];
    const float* g1_asrc = (const float*)d_in[11];
    const float* g1_adst = (const float*)d_in[12];
    const float* g1_b    = (const float*)d_in[13];
    const float* g2_lin  = (const float*)d_in[14];
    const float* g2_asrc = (const float*)d_in[15];
    const float* g2_adst = (const float*)d_in[16];
    const float* g2_b    = (const float*)d_in[17];
    const float* W       = (const float*)d_in[18];
    float* out = (float*)d_out;

    // workspace layout
    int*   count1 = (int*)d_ws;                  // N1
    int*   count2 = count1 + N1;                 // N2
    int*   slot1  = count2 + N2;                 // N1*64
    int*   slot2  = slot1 + N1 * MAXDEG;         // N2*64
    float* h1     = (float*)(slot2 + N2 * MAXDEG);  // N1*200
    float* asrc1  = h1 + N1 * 200;               // N1*4
    float* adst1  = asrc1 + N1 * 4;              // N1*4
    float* x2g    = adst1 + N1 * 4;              // N2*51
    float* x1     = x2g + N2 * F_;               // N1*50
    float* P1t    = x1 + N1 * 50;                // B*64*128
    float* P2     = P1t + B_ * 64 * 128;         // N2*64
    float* h2g    = P2 + N2 * 64;                // N2*4

    hipMemsetAsync(count1, 0, (N1 + N2) * sizeof(int), stream);

    int csr_threads = E1 + N1 + E2 + N2;  // 208896
    k_csr<<<(csr_threads + 255) / 256, 256, 0, stream>>>(e1, e2, count1, slot1, count2, slot2);
    k_prep<<<N1 + N2, 256, 0, stream>>>(cat1, num1, cat2, num2, emb0, emb1, emb2,
                                        g1_lin, g1_asrc, g1_adst, h1, asrc1, adst1, x2g);
    k_gat1<<<N1 / 4, 256, 0, stream>>>(count1, slot1, h1, asrc1, adst1, g1_b, x1);
    k_proj<<<(N1 + N2) * 64 / 256, 256, 0, stream>>>(x1, x2g, W, P1t, P2);
    k_attn<<<B_ * FUTURE, 128, 0, stream>>>(P1t, P2, A, num1, x2g, g2_lin, h2g);
    k_gat2<<<N2 / 4, 256, 0, stream>>>(count2, slot2, h2g, g2_asrc, g2_adst, g2_b, out);
}

// Round 4
// 159.990 us; speedup vs baseline: 1.0800x; 1.0800x over previous
//
#include <hip/hip_runtime.h>

static constexpr int B_ = 64, PAST = 128, FUTURE = 64, F_ = 51;
static constexpr int N1 = B_ * PAST;    // 8192
static constexpr int N2 = B_ * FUTURE;  // 4096
static constexpr int E1 = N1 * 16;      // 131072
static constexpr int E2 = N2 * 16;      // 65536
static constexpr int MAXDEG = 64;
static constexpr int CSR_TOT = E1 + N1 + E2 + N2 + FUTURE * PAST;  // 217088

// node feature t of _pre(): [emb0[c0] (16) | emb1[c1] (8) | emb2[c2] (24) | num (3)]
__device__ __forceinline__
float node_feat(const int* cat, const float* num, const float* e0, const float* e1,
                const float* e2, int n, int t) {
    if (t < 16) return e0[cat[n * 3 + 0] * 16 + t];
    if (t < 24) return e1[cat[n * 3 + 1] * 8 + (t - 16)];
    if (t < 48) return e2[cat[n * 3 + 2] * 24 + (t - 24)];
    return num[n * 3 + (t - 48)];
}

// K1: blocks [0,N1): past -> h1, asrc1, adst1, y1. Blocks [N1,N1+N2): future ->
// x2g row + fused P2 = x2[:, :50] @ W. First 48 future blocks also zero counts.
__global__ __launch_bounds__(256) void k_prep(
        const int* __restrict__ cat1, const float* __restrict__ num1,
        const int* __restrict__ cat2, const float* __restrict__ num2,
        const float* __restrict__ emb0, const float* __restrict__ emb1,
        const float* __restrict__ emb2,
        const float* __restrict__ g1_lin, const float* __restrict__ g1_asrc,
        const float* __restrict__ g1_adst, const float* __restrict__ W,
        float* __restrict__ h1, float* __restrict__ asrc1, float* __restrict__ adst1,
        float* __restrict__ y1, float* __restrict__ x2g, float* __restrict__ P2,
        int* __restrict__ countall) {
    __shared__ float xrow[F_];
    __shared__ float redS[200];
    __shared__ float redD[200];
    int blk = blockIdx.x, t = threadIdx.x;
    if (blk >= N1) {
        int n = blk - N1;
        if (n < 48) countall[n * 256 + t] = 0;   // 48*256 == N1+N2 count ints
        if (t < F_) {
            float xv = node_feat(cat2, num2, emb0, emb1, emb2, n, t);
            xrow[t] = xv;
            x2g[n * F_ + t] = xv;
        }
        __syncthreads();
        if (t < 64) {
            float acc = 0.f;
            for (int j = 0; j < 50; ++j) acc += xrow[j] * W[j * 64 + t];
            P2[n * 64 + t] = acc;
        }
        return;
    }
    int n = blk;
    if (t < F_) {
        float xv = node_feat(cat1, num1, emb0, emb1, emb2, n, t);
        xrow[t] = xv;
        if (t == 50) y1[n] = xv;                  // y_past = x[:, 50]
    }
    __syncthreads();
    if (t < 200) {
        float acc = 0.f;
        for (int j = 0; j < F_; ++j) acc += xrow[j] * g1_lin[j * 200 + t];
        h1[n * 200 + t] = acc;
        redS[t] = acc * g1_asrc[t];               // flat t == h*50+c
        redD[t] = acc * g1_adst[t];
    }
    __syncthreads();
    if (t < 4) {
        float s = 0.f;
        for (int c = 0; c < 50; ++c) s += redS[t * 50 + c];
        asrc1[n * 4 + t] = s;
    } else if (t < 8) {
        int h = t - 4;
        float s = 0.f;
        for (int c = 0; c < 50; ++c) s += redD[h * 50 + c];
        adst1[n * 4 + h] = s;
    }
}

// K2: inverted adjacency for both graphs (+self loops) + transposed mask.
__global__ __launch_bounds__(256) void k_csr(
        const int* __restrict__ e1, const int* __restrict__ e2,
        const int* __restrict__ A,
        int* __restrict__ count1, int* __restrict__ slot1,
        int* __restrict__ count2, int* __restrict__ slot2,
        int* __restrict__ maskT) {
    int i = blockIdx.x * blockDim.x + threadIdx.x;
    if (i < E1) {
        int src = e1[i], dst = e1[E1 + i];
        int pos = atomicAdd(&count1[dst], 1);
        if (pos < MAXDEG) slot1[dst * MAXDEG + pos] = src;
    } else if (i < E1 + N1) {
        int n = i - E1;
        int pos = atomicAdd(&count1[n], 1);
        if (pos < MAXDEG) slot1[n * MAXDEG + pos] = n;
    } else if (i < E1 + N1 + E2) {
        int k = i - E1 - N1;
        int src = e2[k], dst = e2[E2 + k];
        int pos = atomicAdd(&count2[dst], 1);
        if (pos < MAXDEG) slot2[dst * MAXDEG + pos] = src;
    } else if (i < E1 + N1 + E2 + N2) {
        int n = i - E1 - N1 - E2;
        int pos = atomicAdd(&count2[n], 1);
        if (pos < MAXDEG) slot2[n * MAXDEG + pos] = n;
    } else if (i < CSR_TOT) {
        int k = i - (E1 + N1 + E2 + N2);          // k = f*128 + p
        int f = k >> 7, pp = k & 127;
        maskT[k] = A[pp * 192 + PAST + f];
    }
}

// K3: GAT1 aggregation, one wave per dst node; fused x1 -> P1 projection.
// Edge weights staged to LDS (no per-iteration shfl chain). P1 stored row-major.
__global__ __launch_bounds__(256) void k_gat1(
        const int* __restrict__ count1, const int* __restrict__ slot1,
        const float* __restrict__ h1, const float* __restrict__ asrc1,
        const float* __restrict__ adst1, const float* __restrict__ g1_b,
        const float* __restrict__ W, float* __restrict__ P1) {
    __shared__ int   Ssrc[4][64];
    __shared__ float Sw[4][4][64];
    __shared__ float Sx[4][64];
    int t = threadIdx.x, lane = t & 63, wv = t >> 6;
    int n = (blockIdx.x * 256 + t) >> 6;          // one node per wave (grid exact)
    int deg = min(count1[n], MAXDEG);
    int my_src = (lane < deg) ? slot1[n * MAXDEG + lane] : 0;
    float ad0 = adst1[n * 4 + 0], ad1 = adst1[n * 4 + 1];
    float ad2 = adst1[n * 4 + 2], ad3 = adst1[n * 4 + 3];
    float ex0 = 0.f, ex1 = 0.f, ex2 = 0.f, ex3 = 0.f;
    if (lane < deg) {
        float e0 = asrc1[my_src * 4 + 0] + ad0;
        float e1 = asrc1[my_src * 4 + 1] + ad1;
        float e2 = asrc1[my_src * 4 + 2] + ad2;
        float e3 = asrc1[my_src * 4 + 3] + ad3;
        e0 = e0 >= 0.f ? e0 : 0.2f * e0;  ex0 = __expf(e0);
        e1 = e1 >= 0.f ? e1 : 0.2f * e1;  ex1 = __expf(e1);
        e2 = e2 >= 0.f ? e2 : 0.2f * e2;  ex2 = __expf(e2);
        e3 = e3 >= 0.f ? e3 : 0.2f * e3;  ex3 = __expf(e3);
    }
    float s0 = ex0, s1 = ex1, s2 = ex2, s3 = ex3;
    #pragma unroll
    for (int m = 32; m >= 1; m >>= 1) {
        s0 += __shfl_xor(s0, m);
        s1 += __shfl_xor(s1, m);
        s2 += __shfl_xor(s2, m);
        s3 += __shfl_xor(s3, m);
    }
    Ssrc[wv][lane] = my_src;
    Sw[wv][0][lane] = ex0 / (s0 + 1e-16f);
    Sw[wv][1][lane] = ex1 / (s1 + 1e-16f);
    Sw[wv][2][lane] = ex2 / (s2 + 1e-16f);
    Sw[wv][3][lane] = ex3 / (s3 + 1e-16f);
    __syncthreads();
    float acc0 = 0.f, acc1 = 0.f, acc2 = 0.f, acc3 = 0.f;
    for (int i = 0; i < deg; ++i) {
        int srci = Ssrc[wv][i];
        float w0 = Sw[wv][0][i], w1 = Sw[wv][1][i];
        float w2 = Sw[wv][2][i], w3 = Sw[wv][3][i];
        if (lane < 50) {
            const float* hr = &h1[srci * 200];
            acc0 += w0 * hr[lane];
            acc1 += w1 * hr[50 + lane];
            acc2 += w2 * hr[100 + lane];
            acc3 += w3 * hr[150 + lane];
        }
    }
    if (lane < 50)
        Sx[wv][lane] = 0.25f * (acc0 + acc1 + acc2 + acc3) + g1_b[lane];
    __syncthreads();
    float a = 0.f;
    for (int j = 0; j < 50; ++j) a += Sx[wv][j] * W[j * 64 + lane];
    P1[n * 64 + lane] = a;                        // coalesced row-major store
}

// K4: attention + tmp + fused h2 = x2b @ g2_lin.
// Block = (b, group of 16 f). P1 panel transposed into padded LDS once.
__global__ __launch_bounds__(256) void k_attn(
        const float* __restrict__ P1, const float* __restrict__ P2,
        const int* __restrict__ maskT, const float* __restrict__ y1,
        const float* __restrict__ x2g, const float* __restrict__ g2_lin,
        float* __restrict__ h2g) {
    __shared__ float P1s[64 * 129];               // [k][p], pad 129 -> 2-way banks
    __shared__ float ys[128];
    int b = blockIdx.x >> 2, fg = blockIdx.x & 3;
    int t = threadIdx.x, lane = t & 63, wv = t >> 6;
    const float* P1b = P1 + b * 8192;
    for (int i = t; i < 8192; i += 256) {
        int pp = i >> 6, kk = i & 63;             // P1b[i] = P1[b][pp][kk]
        P1s[kk * 129 + pp] = P1b[i];
    }
    if (t < 128) ys[t] = y1[b * 128 + t];
    __syncthreads();
    for (int j = 0; j < 4; ++j) {
        int f = fg * 16 + wv * 4 + j;
        int q = b * 64 + f;
        float p2k = P2[q * 64 + lane];            // lane holds k-th component
        float d2a = 0.f, d2b = 0.f;
        for (int k = 0; k < 64; ++k) {
            float bk = __shfl(p2k, k);
            float va = P1s[k * 129 + lane] - bk;
            float vb = P1s[k * 129 + 64 + lane] - bk;
            d2a += va * va;
            d2b += vb * vb;
        }
        int ma = maskT[f * 128 + lane];
        int mb = maskT[f * 128 + 64 + lane];
        float va = ma ? -d2a : -1e30f;
        float vb = mb ? -d2b : -1e30f;
        float mx = fmaxf(va, vb);
        #pragma unroll
        for (int m = 32; m >= 1; m >>= 1) mx = fmaxf(mx, __shfl_xor(mx, m));
        float wa = ma ? __expf(va - mx) : 0.f;
        float wb = mb ? __expf(vb - mx) : 0.f;
        float sw = wa + wb;
        float sy = wa * ys[lane] + wb * ys[64 + lane];
        #pragma unroll
        for (int m = 32; m >= 1; m >>= 1) {
            sw += __shfl_xor(sw, m);
            sy += __shfl_xor(sy, m);
        }
        float tsh = sy / sw;
        float xv = (lane < 50) ? x2g[q * F_ + lane] : 0.f;
        #pragma unroll
        for (int h = 0; h < 4; ++h) {
            float c = xv * g2_lin[lane * 4 + h];  // lanes >=50 contribute 0 via xv
            #pragma unroll
            for (int m = 32; m >= 1; m >>= 1) c += __shfl_xor(c, m);
            c += tsh * g2_lin[50 * 4 + h];
            if (lane == h) h2g[q * 4 + h] = c;
        }
    }
}

// K5: GAT2 aggregation (out_ch=1): one wave per dst node.
__global__ __launch_bounds__(256) void k_gat2(
        const int* __restrict__ count2, const int* __restrict__ slot2,
        const float* __restrict__ h2g, const float* __restrict__ g2_asrc,
        const float* __restrict__ g2_adst, const float* __restrict__ g2_b,
        float* __restrict__ out) {
    int wave = (blockIdx.x * blockDim.x + threadIdx.x) >> 6;
    int lane = threadIdx.x & 63;
    if (wave >= N2) return;
    int n = wave;
    int deg = min(count2[n], MAXDEG);
    int my_src = (lane < deg) ? slot2[n * MAXDEG + lane] : 0;
    float ex[4], nm[4], adterm[4], as[4];
    #pragma unroll
    for (int h = 0; h < 4; ++h) {
        as[h] = g2_asrc[h];
        adterm[h] = h2g[n * 4 + h] * g2_adst[h];
        ex[h] = 0.f; nm[h] = 0.f;
    }
    if (lane < deg) {
        #pragma unroll
        for (int h = 0; h < 4; ++h) {
            float hs = h2g[my_src * 4 + h];
            float e = hs * as[h] + adterm[h];
            e = e >= 0.f ? e : 0.2f * e;
            float xv = __expf(e);
            ex[h] = xv;
            nm[h] = xv * hs;
        }
    }
    #pragma unroll
    for (int m = 32; m >= 1; m >>= 1) {
        #pragma unroll
        for (int h = 0; h < 4; ++h) {
            ex[h] += __shfl_xor(ex[h], m);
            nm[h] += __shfl_xor(nm[h], m);
        }
    }
    if (lane == 0) {
        float o = 0.f;
        #pragma unroll
        for (int h = 0; h < 4; ++h) o += nm[h] / (ex[h] + 1e-16f);
        out[n] = 0.25f * o + g2_b[0];
    }
}

extern "C" void kernel_launch(void* const* d_in, const int* in_sizes, int n_in,
                              void* d_out, int out_size, void* d_ws, size_t ws_size,
                              hipStream_t stream) {
    const int*   cat1    = (const int*)  d_in[0];
    const float* num1    = (const float*)d_in[1];
    const int*   cat2    = (const int*)  d_in[2];
    const float* num2    = (const float*)d_in[3];
    const int*   e1      = (const int*)  d_in[4];
    const int*   e2      = (const int*)  d_in[5];
    const int*   A       = (const int*)  d_in[6];
    const float* emb0    = (const float*)d_in[7];
    const float* emb1    = (const float*)d_in[8];
    const float* emb2    = (const float*)d_in[9];
    const float* g1_lin  = (const float*)d_in[10];
    const float* g1_asrc = (const float*)d_in[11];
    const float* g1_adst = (const float*)d_in[12];
    const float* g1_b    = (const float*)d_in[13];
    const float* g2_lin  = (const float*)d_in[14];
    const float* g2_asrc = (const float*)d_in[15];
    const float* g2_adst = (const float*)d_in[16];
    const float* g2_b    = (const float*)d_in[17];
    const float* W       = (const float*)d_in[18];
    float* out = (float*)d_out;

    // workspace layout (fp32/int32 elements)
    int*   count1 = (int*)d_ws;                   // N1        (count1+count2 contiguous!)
    int*   count2 = count1 + N1;                  // N2
    int*   slot1  = count2 + N2;                  // N1*64
    int*   slot2  = slot1 + N1 * MAXDEG;          // N2*64
    int*   maskT  = slot2 + N2 * MAXDEG;          // 64*128
    float* h1     = (float*)(maskT + FUTURE * PAST);  // N1*200
    float* asrc1  = h1 + N1 * 200;                // N1*4
    float* adst1  = asrc1 + N1 * 4;               // N1*4
    float* y1     = adst1 + N1 * 4;               // N1
    float* x2g    = y1 + N1;                      // N2*51
    float* P1     = x2g + N2 * F_;                // N1*64
    float* P2     = P1 + N1 * 64;                 // N2*64
    float* h2g    = P2 + N2 * 64;                 // N2*4

    k_prep<<<N1 + N2, 256, 0, stream>>>(cat1, num1, cat2, num2, emb0, emb1, emb2,
                                        g1_lin, g1_asrc, g1_adst, W,
                                        h1, asrc1, adst1, y1, x2g, P2, count1);
    k_csr<<<CSR_TOT / 256, 256, 0, stream>>>(e1, e2, A, count1, slot1, count2, slot2, maskT);
    k_gat1<<<N1 / 4, 256, 0, stream>>>(count1, slot1, h1, asrc1, adst1, g1_b, W, P1);
    k_attn<<<B_ * 4, 256, 0, stream>>>(P1, P2, maskT, y1, x2g, g2_lin, h2g);
    k_gat2<<<N2 / 4, 256, 0, stream>>>(count2, slot2, h2g, g2_asrc, g2_adst, g2_b, out);
}